// Round 5
// baseline (96.316 us; speedup 1.0000x reference)
//
#include <hip/hip_runtime.h>
#include <math.h>

// B=32, C=3, H=W=512. Low-pass keeps freqs {0,1,2,-3,-2,-1} in both dims.
// Pipeline (3 kernels):
//   k_tab:    synthesis twiddle table tabS[512][12] (for k_out only)
//   k_colfft: per (img, 16-row slab): each thread loads 8 float4 of x upfront,
//             accumulates A[k][w] (k=0..3) via register phasor recurrence
//             (compile-time rotation constants), projects its 4 w-columns onto
//             col freqs m=-3..3 in registers, shfl-butterfly + LDS reduce ->
//             P[img][chunk][28][2]
//   k_out:    parallel chunk-reduce of P -> F in LDS; per-row T[c][kc]; per
//             pixel synth via register phasor recurrence, |.|, MLP 3->8 relu
//             ->3, +lp, clip.
//
// ws layout (floats): tabS @0 ([512][12]), P @6144 ([96][32][28][2]) ~700 KB.

#define WS_TS 0
#define WS_P  6144
constexpr int NCHUNK = 32;
constexpr int HSZ = 512 / NCHUNK;   // 16 rows per block

__global__ __launch_bounds__(256) void k_tab(float* __restrict__ ws) {
    int h = blockIdx.x * 256 + threadIdx.x;
    if (h >= 512) return;
    const float STEP = 6.28318530717958647692f / 512.0f;
    const int mv[6] = {0, 1, 2, -3, -2, -1};
    float* tsp = ws + WS_TS + h * 12;
#pragma unroll
    for (int i = 0; i < 6; ++i) {
        int r = ((mv[i] * h) % 512 + 512) & 511;
        float s, c;
        sincosf(STEP * (float)r, &s, &c);
        tsp[2 * i] = c; tsp[2 * i + 1] = s;
    }
}

__device__ __forceinline__ float wredsum(float v) {
#pragma unroll
    for (int st = 1; st < 64; st <<= 1) v += __shfl_xor(v, st, 64);
    return v;
}

// Block = (img, 16-row slab). 256 threads: half = t>>7 handles even/odd rows,
// lane tl = t&127 owns w-quad w0 = tl*4. All loads issued upfront; all
// twiddles/projection phasors by register recurrence; butterfly reduce.
__global__ __launch_bounds__(256, 4) void k_colfft(const float* __restrict__ x,
                                                   float* __restrict__ ws) {
    __shared__ float Rs4[4][56];
    float* P = ws + WS_P;
    int img = blockIdx.x / NCHUNK;
    int chunk = blockIdx.x % NCHUNK;
    int t = threadIdx.x;
    int half = t >> 7;
    int tl = t & 127;
    int w0 = tl * 4;
    int h0 = chunk * HSZ;
    int wv = t >> 6;

    const float* xb = x + (size_t)img * 262144 + (size_t)(h0 + half) * 512 + w0;

    // 8 independent row loads, all in flight
    float4 r[8];
#pragma unroll
    for (int j = 0; j < 8; ++j)
        r[j] = *(const float4*)(xb + (size_t)j * 1024);

    const float TH = 6.28318530717958647692f / 512.0f;
    // row phasors (cos(k h th), sin(k h th)) at h = h0+half; k=0 folds to (1,0)
    float pc[4], ps[4];
    pc[0] = 1.f; ps[0] = 0.f;
    sincosf(TH * (float)(h0 + half), &ps[1], &pc[1]);
    pc[2] = pc[1] * pc[1] - ps[1] * ps[1];
    ps[2] = 2.f * pc[1] * ps[1];
    pc[3] = pc[1] * pc[2] - ps[1] * ps[2];
    ps[3] = ps[1] * pc[2] + pc[1] * ps[2];
    // rotation by +2 rows: e^{i 2k th}
    const float RC[4] = {1.f, 0.999698818696204220f, 0.998795456205172393f, 0.997290456678690216f};
    const float RS[4] = {0.f, 0.024541228522912288f, 0.049067674327418015f, 0.073564563599667426f};

    float ar[4][4], ai[4][4];
#pragma unroll
    for (int k = 0; k < 4; ++k)
#pragma unroll
        for (int q = 0; q < 4; ++q) { ar[k][q] = 0.f; ai[k][q] = 0.f; }

#pragma unroll
    for (int j = 0; j < 8; ++j) {
        float xv[4] = {r[j].x, r[j].y, r[j].z, r[j].w};
#pragma unroll
        for (int k = 0; k < 4; ++k) {
#pragma unroll
            for (int q = 0; q < 4; ++q) {
                ar[k][q] = fmaf(xv[q], pc[k], ar[k][q]);
                ai[k][q] = fmaf(-xv[q], ps[k], ai[k][q]);
            }
            if (j < 7) {
                float nc = pc[k] * RC[k] - ps[k] * RS[k];
                float ns = ps[k] * RC[k] + pc[k] * RS[k];
                pc[k] = nc; ps[k] = ns;
            }
        }
    }

    // ---- projection onto column freqs m = -3..3, pair = k*7 + (m+3) ----
    // m = 0: direct sums
#pragma unroll
    for (int k = 0; k < 4; ++k) {
        float d1 = ar[k][0] + ar[k][1] + ar[k][2] + ar[k][3];
        float d3 = ai[k][0] + ai[k][1] + ai[k][2] + ai[k][3];
        d1 = wredsum(d1); d3 = wredsum(d3);
        if ((t & 63) == 0) {
            Rs4[wv][(k * 7 + 3) * 2]     = d1;
            Rs4[wv][(k * 7 + 3) * 2 + 1] = d3;
        }
    }
    // m = 1..3: phasor (cos(m w th), sin(m w th)) at w = w0..w0+3 by recurrence;
    // d-split yields both +m and -m from 16 FMA.
    const float MC[3] = {0.999924701839144503f, 0.999698818696204220f, 0.999322384588349544f};
    const float MS[3] = {0.012271538285719925f, 0.024541228522912288f, 0.036807222941358832f};
#pragma unroll
    for (int im = 0; im < 3; ++im) {
        int m = im + 1;
        float pj[4], sj[4];
        sincosf(TH * (float)(m * w0), &sj[0], &pj[0]);
#pragma unroll
        for (int j = 0; j < 3; ++j) {
            pj[j + 1] = pj[j] * MC[im] - sj[j] * MS[im];
            sj[j + 1] = sj[j] * MC[im] + pj[j] * MS[im];
        }
#pragma unroll
        for (int k = 0; k < 4; ++k) {
            float e1 = 0.f, e2 = 0.f, e3 = 0.f, e4 = 0.f;
#pragma unroll
            for (int j = 0; j < 4; ++j) {
                e1 = fmaf(ar[k][j], pj[j], e1);
                e2 = fmaf(ai[k][j], sj[j], e2);
                e3 = fmaf(ai[k][j], pj[j], e3);
                e4 = fmaf(ar[k][j], sj[j], e4);
            }
            e1 = wredsum(e1); e2 = wredsum(e2); e3 = wredsum(e3); e4 = wredsum(e4);
            if ((t & 63) == 0) {
                int pp = k * 7 + 3 + m, pn = k * 7 + 3 - m;
                Rs4[wv][pp * 2]     = e1 + e2;   // A * e^{-i m w th}
                Rs4[wv][pp * 2 + 1] = e3 - e4;
                Rs4[wv][pn * 2]     = e1 - e2;   // A * e^{+i m w th}
                Rs4[wv][pn * 2 + 1] = e3 + e4;
            }
        }
    }
    __syncthreads();
    if (t < 56) {
        float s = Rs4[0][t] + Rs4[1][t] + Rs4[2][t] + Rs4[3][t];
        P[(size_t)(img * NCHUNK + chunk) * 56 + t] = s;
    }
}

__global__ __launch_bounds__(256) void k_out(const float* __restrict__ ws,
                                             const float* __restrict__ w1,
                                             const float* __restrict__ b1,
                                             const float* __restrict__ w2,
                                             const float* __restrict__ b2,
                                             float* __restrict__ out) {
    const float* tabS = ws + WS_TS;
    const float* P = ws + WS_P;
    __shared__ float F_lds[3][56];
    __shared__ float T[4][3][12];
    int t = threadIdx.x;
    int blk = blockIdx.x;
    int b = blk >> 7;
    int h0 = (blk & 127) << 2;

    // parallel chunk-reduce: F (raw sums) into LDS
    if (t < 168) {
        int c = t / 56, comp = t % 56;
        const float* Pb = P + (size_t)(b * 3 + c) * NCHUNK * 56 + comp;
        float s = 0.f;
#pragma unroll 8
        for (int ch = 0; ch < NCHUNK; ++ch) s += Pb[ch * 56];
        F_lds[c][comp] = s;
    }

    float rw1[8][3], rb1[8], rw2[3][8], rb2[3];
#pragma unroll
    for (int f_ = 0; f_ < 8; ++f_) {
        rb1[f_] = b1[f_];
#pragma unroll
        for (int c = 0; c < 3; ++c) rw1[f_][c] = w1[f_ * 3 + c];
    }
#pragma unroll
    for (int c = 0; c < 3; ++c) {
        rb2[c] = b2[c];
#pragma unroll
        for (int f_ = 0; f_ < 8; ++f_) rw2[c][f_] = w2[c * 8 + f_];
    }
    __syncthreads();

    if (t < 72) {
        int rl = t / 18, rem = t % 18;
        int c = rem / 6, kc = rem % 6;
        int h = h0 + rl;
        const float* th = tabS + h * 12;
        int m_kc = (kc < 3) ? kc : kc - 6;
        const float inv = 1.0f / (512.0f * 512.0f);
        float tre = 0.f, tim = 0.f;
#pragma unroll
        for (int kr = 0; kr < 6; ++kr) {
            int kk, mi; float csign;
            if (kr < 3) { kk = kr;     mi = m_kc + 3; csign =  1.f; }
            else        { kk = 6 - kr; mi = 3 - m_kc; csign = -1.f; }
            int pair = kk * 7 + mi;
            float fr = F_lds[c][pair * 2] * inv;
            float fi = F_lds[c][pair * 2 + 1] * csign * inv;
            float cc = th[kr * 2], ss = th[kr * 2 + 1];
            tre += fr * cc - fi * ss;    // * e^{+i m_r h theta}
            tim += fr * ss + fi * cc;
        }
        T[rl][c][kc * 2]     = tre;
        T[rl][c][kc * 2 + 1] = tim;
    }
    __syncthreads();

    int rl = t >> 6, lane = t & 63;
    int h = h0 + rl;
    // fold +/- frequency pairs: S = A0 + (U1,V1) e1 + (U2,V2) e2 + B e{-3}
    float A0r[3], A0i[3], U1r[3], U1i[3], V1r[3], V1i[3];
    float U2r[3], U2i[3], V2r[3], V2i[3], Br[3], Bi[3];
#pragma unroll
    for (int c = 0; c < 3; ++c) {
        const float* Tc = T[rl][c];
        A0r[c] = Tc[0];  A0i[c] = Tc[1];
        float t1r = Tc[2],  t1i = Tc[3];    // m=+1
        float t2r = Tc[4],  t2i = Tc[5];    // m=+2
        float bmr = Tc[6],  bmi = Tc[7];    // m=-3
        float m2r = Tc[8],  m2i = Tc[9];    // m=-2
        float m1r = Tc[10], m1i = Tc[11];   // m=-1
        U1r[c] = t1r + m1r; U1i[c] = t1i + m1i;
        V1r[c] = t1r - m1r; V1i[c] = t1i - m1i;
        U2r[c] = t2r + m2r; U2i[c] = t2i + m2i;
        V2r[c] = t2r - m2r; V2i[c] = t2i - m2i;
        Br[c] = bmr; Bi[c] = bmi;
    }
    // phasors e^{+2pi i p w/512}, p=1,2,3, init at w=lane from table
    const float* tw = tabS + lane * 12;
    float c1 = tw[2], s1 = tw[3];
    float c2 = tw[4], s2 = tw[5];
    float c3 = tw[6], s3 = -tw[7];          // entry 3 stores m=-3
    const float K = 0.70710678118654752440f;
    float* ob = out + ((size_t)(b * 3) * 512 + h) * 512;

#pragma unroll
    for (int j = 0; j < 8; ++j) {
        int w = lane + 64 * j;
        float lp[3];
#pragma unroll
        for (int c = 0; c < 3; ++c) {
            float re = A0r[c] + U1r[c] * c1 - V1i[c] * s1
                              + U2r[c] * c2 - V2i[c] * s2
                              + Br[c] * c3 + Bi[c] * s3;
            float im = A0i[c] + U1i[c] * c1 + V1r[c] * s1
                              + U2i[c] * c2 + V2r[c] * s2
                              + Bi[c] * c3 - Br[c] * s3;
            lp[c] = sqrtf(re * re + im * im);
        }
        float hid[8];
#pragma unroll
        for (int f_ = 0; f_ < 8; ++f_) {
            float v = rb1[f_] + lp[0] * rw1[f_][0] + lp[1] * rw1[f_][1] + lp[2] * rw1[f_][2];
            hid[f_] = fmaxf(v, 0.0f);
        }
#pragma unroll
        for (int c = 0; c < 3; ++c) {
            float y = rb2[c] + lp[c];
#pragma unroll
            for (int f_ = 0; f_ < 8; ++f_) y += hid[f_] * rw2[c][f_];
            y = fminf(fmaxf(y, 0.0f), 1.0f);
            ob[(size_t)c * 262144 + w] = y;
        }
        if (j < 7) {  // advance phasors by e^{+i pi p/4}
            float nc1 = K * (c1 - s1), ns1 = K * (c1 + s1);
            float nc2 = -s2,           ns2 = c2;
            float nc3 = -K * (c3 + s3), ns3 = K * (c3 - s3);
            c1 = nc1; s1 = ns1; c2 = nc2; s2 = ns2; c3 = nc3; s3 = ns3;
        }
    }
}

extern "C" void kernel_launch(void* const* d_in, const int* in_sizes, int n_in,
                              void* d_out, int out_size, void* d_ws, size_t ws_size,
                              hipStream_t stream) {
    const float* x  = (const float*)d_in[0];
    const float* w1 = (const float*)d_in[1];
    const float* b1 = (const float*)d_in[2];
    const float* w2 = (const float*)d_in[3];
    const float* b2 = (const float*)d_in[4];
    float* out = (float*)d_out;
    float* ws = (float*)d_ws;

    hipLaunchKernelGGL(k_tab, dim3(2), dim3(256), 0, stream, ws);
    hipLaunchKernelGGL(k_colfft, dim3(96 * NCHUNK), dim3(256), 0, stream, x, ws);
    hipLaunchKernelGGL(k_out, dim3(4096), dim3(256), 0, stream, ws, w1, b1, w2, b2, out);
}

// Round 6
// 71.015 us; speedup vs baseline: 1.3563x; 1.3563x over previous
//
#include <hip/hip_runtime.h>
#include <math.h>

// B=32, C=3, H=W=512. Low-pass keeps freqs {0,1,2,-3,-2,-1} in both dims.
// Pipeline (4 kernels, NO cross-lane ops anywhere):
//   k_tab:    synthesis twiddle table tabS[512][12] (k_out only)
//   k_colsum: threads = w (coalesced); per-thread serial h-sum over 32 rows:
//             A[k][w] = sum_h x[h][w] e^{-2pi i k h/512}, k=0..3 (k0 imag = 0),
//             phasors by register recurrence. One LDS exchange halves partials
//             -> Apart[img][8][plane 8][512]  (12.6 MB)
//   k_proj:   per img: sum 8 partials into LDS As[plane][seg][68], then 224
//             threads project 28 (k,m) pairs via phasor recurrence (each
//             thread writes its own slot), reduce 8 segs -> F[img][56]
//   k_out:    load F, per-row T[c][kc]; per pixel synth via register phasor
//             recurrence, |.|, MLP 3->8 relu ->3, +lp, clip.
//
// ws (floats): tabS @0 (6144), F @6144 (5376), Apart @12288 (3.15M) ~12.6 MB.

#define WS_TS 0
#define WS_F  6144
#define WS_A  12288
constexpr int NPART = 8;    // partials per image (after in-block halving)
constexpr int ROWS = 32;    // rows per thread in k_colsum

__global__ __launch_bounds__(256) void k_tab(float* __restrict__ ws) {
    int h = blockIdx.x * 256 + threadIdx.x;
    if (h >= 512) return;
    const float STEP = 6.28318530717958647692f / 512.0f;
    const int mv[6] = {0, 1, 2, -3, -2, -1};
    float* tsp = ws + WS_TS + h * 12;
#pragma unroll
    for (int i = 0; i < 6; ++i) {
        int r = ((mv[i] * h) % 512 + 512) & 511;
        float s, c;
        sincosf(STEP * (float)r, &s, &c);
        tsp[2 * i] = c; tsp[2 * i + 1] = s;
    }
}

// Block = (img, hg-pair). t&127 -> w-quad; t>>7 -> which 32-row group.
// Pure streaming: 32 coalesced float4 loads + register FMA; no shuffles.
__global__ __launch_bounds__(256) void k_colsum(const float* __restrict__ x,
                                                float* __restrict__ ws) {
    __shared__ float Xc[128][29];
    float* A = ws + WS_A;
    int img = blockIdx.x >> 3;
    int hgp = blockIdx.x & 7;
    int t = threadIdx.x;
    int wq = t & 127;
    int hl = t >> 7;
    int h0 = (hgp * 2 + hl) * ROWS;
    const float* xp = x + (size_t)img * 262144 + (size_t)h0 * 512 + wq * 4;

    const float TH = 6.28318530717958647692f / 512.0f;
    float pc1, ps1, pc2, ps2, pc3, ps3;
    sincosf(TH * (float)h0, &ps1, &pc1);
    pc2 = pc1 * pc1 - ps1 * ps1;  ps2 = 2.f * pc1 * ps1;
    pc3 = pc1 * pc2 - ps1 * ps2;  ps3 = ps1 * pc2 + pc1 * ps2;
    const float C1 = 0.99992470183914450299f, S1 = 0.01227153828571992539f;
    const float C2 = 0.99969881869620422012f, S2 = 0.02454122852291228803f;
    const float C3 = 0.99932238458834954375f, S3 = 0.03680722294135883171f;

    float s0[4] = {0,0,0,0};
    float ar1[4] = {0,0,0,0}, ai1[4] = {0,0,0,0};
    float ar2[4] = {0,0,0,0}, ai2[4] = {0,0,0,0};
    float ar3[4] = {0,0,0,0}, ai3[4] = {0,0,0,0};

#pragma unroll 4
    for (int i = 0; i < ROWS; ++i) {
        float4 xv = *(const float4*)(xp + (size_t)i * 512);
        float xa[4] = {xv.x, xv.y, xv.z, xv.w};
#pragma unroll
        for (int q = 0; q < 4; ++q) {
            s0[q] += xa[q];
            ar1[q] = fmaf(xa[q], pc1, ar1[q]);  ai1[q] = fmaf(-xa[q], ps1, ai1[q]);
            ar2[q] = fmaf(xa[q], pc2, ar2[q]);  ai2[q] = fmaf(-xa[q], ps2, ai2[q]);
            ar3[q] = fmaf(xa[q], pc3, ar3[q]);  ai3[q] = fmaf(-xa[q], ps3, ai3[q]);
        }
        float n;
        n = pc1 * C1 - ps1 * S1;  ps1 = ps1 * C1 + pc1 * S1;  pc1 = n;
        n = pc2 * C2 - ps2 * S2;  ps2 = ps2 * C2 + pc2 * S2;  pc2 = n;
        n = pc3 * C3 - ps3 * S3;  ps3 = ps3 * C3 + pc3 * S3;  pc3 = n;
    }

    // halve the two 32-row groups via one LDS exchange (no shuffles)
    if (hl == 1) {
        float* r = &Xc[wq][0];
#pragma unroll
        for (int q = 0; q < 4; ++q) {
            r[q]      = s0[q];
            r[4 + q]  = ar1[q];  r[8 + q]  = ai1[q];
            r[12 + q] = ar2[q];  r[16 + q] = ai2[q];
            r[20 + q] = ar3[q];  r[24 + q] = ai3[q];
        }
    }
    __syncthreads();
    if (hl == 0) {
        const float* r = &Xc[wq][0];
        float* Ab = A + (((size_t)img * NPART + hgp) * 8) * 512 + wq * 4;
        *(float4*)(Ab + 0 * 512) = make_float4(s0[0] + r[0], s0[1] + r[1], s0[2] + r[2], s0[3] + r[3]);
        *(float4*)(Ab + 1 * 512) = make_float4(0.f, 0.f, 0.f, 0.f);
        *(float4*)(Ab + 2 * 512) = make_float4(ar1[0] + r[4],  ar1[1] + r[5],  ar1[2] + r[6],  ar1[3] + r[7]);
        *(float4*)(Ab + 3 * 512) = make_float4(ai1[0] + r[8],  ai1[1] + r[9],  ai1[2] + r[10], ai1[3] + r[11]);
        *(float4*)(Ab + 4 * 512) = make_float4(ar2[0] + r[12], ar2[1] + r[13], ar2[2] + r[14], ar2[3] + r[15]);
        *(float4*)(Ab + 5 * 512) = make_float4(ai2[0] + r[16], ai2[1] + r[17], ai2[2] + r[18], ai2[3] + r[19]);
        *(float4*)(Ab + 6 * 512) = make_float4(ar3[0] + r[20], ar3[1] + r[21], ar3[2] + r[22], ar3[3] + r[23]);
        *(float4*)(Ab + 7 * 512) = make_float4(ai3[0] + r[24], ai3[1] + r[25], ai3[2] + r[26], ai3[3] + r[27]);
    }
}

// Per image: reduce 8 partials -> As (bank-staggered), project 28 pairs.
__global__ __launch_bounds__(256) void k_proj(float* __restrict__ ws) {
    __shared__ float As[8][8][68];    // [plane][seg][j], pad 68 (=4 mod 32)
    __shared__ float Rs[28][8][2];
    const float* A = ws + WS_A;
    float* F = ws + WS_F;
    int img = blockIdx.x;
    int t = threadIdx.x;

    {   // t -> (plane, 16 consecutive w)
        int plane = t >> 5;
        int w0 = (t & 31) * 16;
        float4 acc[4];
#pragma unroll
        for (int q = 0; q < 4; ++q) acc[q] = make_float4(0.f, 0.f, 0.f, 0.f);
        const float* base = A + ((size_t)img * NPART * 8 + plane) * 512 + w0;
        for (int hg = 0; hg < NPART; ++hg) {
            const float* p = base + (size_t)hg * 8 * 512;
#pragma unroll
            for (int q = 0; q < 4; ++q) {
                float4 v = *(const float4*)(p + q * 4);
                acc[q].x += v.x; acc[q].y += v.y; acc[q].z += v.z; acc[q].w += v.w;
            }
        }
        int seg = w0 >> 6, j0 = w0 & 63;
#pragma unroll
        for (int q = 0; q < 4; ++q)
            *(float4*)&As[plane][seg][j0 + q * 4] = acc[q];
    }
    __syncthreads();

    if (t < 224) {
        int pair = t >> 3, seg = t & 7;
        int k = pair / 7, mi = pair % 7;
        float m = (float)(mi - 3);
        const float TH = 6.28318530717958647692f / 512.0f;
        float cm, sm, pc, ps;
        sincosf(-m * TH, &sm, &cm);                       // e^{-i m theta}
        sincosf(-m * TH * (float)(seg * 64), &ps, &pc);   // e^{-i m w0 theta}
        const float* Ar_ = &As[2 * k][seg][0];
        const float* Ai_ = &As[2 * k + 1][seg][0];
        float pre = 0.f, pim = 0.f;
#pragma unroll 4
        for (int j = 0; j < 64; ++j) {
            float Ar = Ar_[j], Ai = Ai_[j];
            pre += Ar * pc - Ai * ps;    // Re[(Ar+iAi)(pc+ips)]
            pim += Ar * ps + Ai * pc;
            float n = pc * cm - ps * sm;
            ps = ps * cm + pc * sm;
            pc = n;
        }
        Rs[pair][seg][0] = pre;
        Rs[pair][seg][1] = pim;
    }
    __syncthreads();
    if (t < 56) {
        int pair = t >> 1, part = t & 1;
        float s = 0.f;
#pragma unroll
        for (int g = 0; g < 8; ++g) s += Rs[pair][g][part];
        F[(size_t)img * 56 + t] = s;
    }
}

__global__ __launch_bounds__(256) void k_out(const float* __restrict__ ws,
                                             const float* __restrict__ w1,
                                             const float* __restrict__ b1,
                                             const float* __restrict__ w2,
                                             const float* __restrict__ b2,
                                             float* __restrict__ out) {
    const float* tabS = ws + WS_TS;
    const float* Fb = ws + WS_F;
    __shared__ float F_lds[3][56];
    __shared__ float T[4][3][12];
    int t = threadIdx.x;
    int blk = blockIdx.x;
    int b = blk >> 7;
    int h0 = (blk & 127) << 2;

    if (t < 168) {
        int c = t / 56, comp = t % 56;
        F_lds[c][comp] = Fb[(size_t)(b * 3 + c) * 56 + comp];
    }

    float rw1[8][3], rb1[8], rw2[3][8], rb2[3];
#pragma unroll
    for (int f_ = 0; f_ < 8; ++f_) {
        rb1[f_] = b1[f_];
#pragma unroll
        for (int c = 0; c < 3; ++c) rw1[f_][c] = w1[f_ * 3 + c];
    }
#pragma unroll
    for (int c = 0; c < 3; ++c) {
        rb2[c] = b2[c];
#pragma unroll
        for (int f_ = 0; f_ < 8; ++f_) rw2[c][f_] = w2[c * 8 + f_];
    }
    __syncthreads();

    if (t < 72) {
        int rl = t / 18, rem = t % 18;
        int c = rem / 6, kc = rem % 6;
        int h = h0 + rl;
        const float* th = tabS + h * 12;
        int m_kc = (kc < 3) ? kc : kc - 6;
        const float inv = 1.0f / (512.0f * 512.0f);
        float tre = 0.f, tim = 0.f;
#pragma unroll
        for (int kr = 0; kr < 6; ++kr) {
            int kk, mi; float csign;
            if (kr < 3) { kk = kr;     mi = m_kc + 3; csign =  1.f; }
            else        { kk = 6 - kr; mi = 3 - m_kc; csign = -1.f; }
            int pair = kk * 7 + mi;
            float fr = F_lds[c][pair * 2] * inv;
            float fi = F_lds[c][pair * 2 + 1] * csign * inv;
            float cc = th[kr * 2], ss = th[kr * 2 + 1];
            tre += fr * cc - fi * ss;    // * e^{+i m_r h theta}
            tim += fr * ss + fi * cc;
        }
        T[rl][c][kc * 2]     = tre;
        T[rl][c][kc * 2 + 1] = tim;
    }
    __syncthreads();

    int rl = t >> 6, lane = t & 63;
    int h = h0 + rl;
    // fold +/- frequency pairs: S = A0 + (U1,V1) e1 + (U2,V2) e2 + B e{-3}
    float A0r[3], A0i[3], U1r[3], U1i[3], V1r[3], V1i[3];
    float U2r[3], U2i[3], V2r[3], V2i[3], Br[3], Bi[3];
#pragma unroll
    for (int c = 0; c < 3; ++c) {
        const float* Tc = T[rl][c];
        A0r[c] = Tc[0];  A0i[c] = Tc[1];
        float t1r = Tc[2],  t1i = Tc[3];    // m=+1
        float t2r = Tc[4],  t2i = Tc[5];    // m=+2
        float bmr = Tc[6],  bmi = Tc[7];    // m=-3
        float m2r = Tc[8],  m2i = Tc[9];    // m=-2
        float m1r = Tc[10], m1i = Tc[11];   // m=-1
        U1r[c] = t1r + m1r; U1i[c] = t1i + m1i;
        V1r[c] = t1r - m1r; V1i[c] = t1i - m1i;
        U2r[c] = t2r + m2r; U2i[c] = t2i + m2i;
        V2r[c] = t2r - m2r; V2i[c] = t2i - m2i;
        Br[c] = bmr; Bi[c] = bmi;
    }
    // phasors e^{+2pi i p w/512}, p=1,2,3, init at w=lane from table
    const float* tw = tabS + lane * 12;
    float c1 = tw[2], s1 = tw[3];
    float c2 = tw[4], s2 = tw[5];
    float c3 = tw[6], s3 = -tw[7];          // entry 3 stores m=-3
    const float K = 0.70710678118654752440f;
    float* ob = out + ((size_t)(b * 3) * 512 + h) * 512;

#pragma unroll
    for (int j = 0; j < 8; ++j) {
        int w = lane + 64 * j;
        float lp[3];
#pragma unroll
        for (int c = 0; c < 3; ++c) {
            float re = A0r[c] + U1r[c] * c1 - V1i[c] * s1
                              + U2r[c] * c2 - V2i[c] * s2
                              + Br[c] * c3 + Bi[c] * s3;
            float im = A0i[c] + U1i[c] * c1 + V1r[c] * s1
                              + U2i[c] * c2 + V2r[c] * s2
                              + Bi[c] * c3 - Br[c] * s3;
            lp[c] = sqrtf(re * re + im * im);
        }
        float hid[8];
#pragma unroll
        for (int f_ = 0; f_ < 8; ++f_) {
            float v = rb1[f_] + lp[0] * rw1[f_][0] + lp[1] * rw1[f_][1] + lp[2] * rw1[f_][2];
            hid[f_] = fmaxf(v, 0.0f);
        }
#pragma unroll
        for (int c = 0; c < 3; ++c) {
            float y = rb2[c] + lp[c];
#pragma unroll
            for (int f_ = 0; f_ < 8; ++f_) y += hid[f_] * rw2[c][f_];
            y = fminf(fmaxf(y, 0.0f), 1.0f);
            ob[(size_t)c * 262144 + w] = y;
        }
        if (j < 7) {  // advance phasors by e^{+i pi p/4}
            float nc1 = K * (c1 - s1), ns1 = K * (c1 + s1);
            float nc2 = -s2,           ns2 = c2;
            float nc3 = -K * (c3 + s3), ns3 = K * (c3 - s3);
            c1 = nc1; s1 = ns1; c2 = nc2; s2 = ns2; c3 = nc3; s3 = ns3;
        }
    }
}

extern "C" void kernel_launch(void* const* d_in, const int* in_sizes, int n_in,
                              void* d_out, int out_size, void* d_ws, size_t ws_size,
                              hipStream_t stream) {
    const float* x  = (const float*)d_in[0];
    const float* w1 = (const float*)d_in[1];
    const float* b1 = (const float*)d_in[2];
    const float* w2 = (const float*)d_in[3];
    const float* b2 = (const float*)d_in[4];
    float* out = (float*)d_out;
    float* ws = (float*)d_ws;

    hipLaunchKernelGGL(k_tab, dim3(2), dim3(256), 0, stream, ws);
    hipLaunchKernelGGL(k_colsum, dim3(96 * 8), dim3(256), 0, stream, x, ws);
    hipLaunchKernelGGL(k_proj, dim3(96), dim3(256), 0, stream, ws);
    hipLaunchKernelGGL(k_out, dim3(4096), dim3(256), 0, stream, ws, w1, b1, w2, b2, out);
}

// Round 7
// 69.738 us; speedup vs baseline: 1.3811x; 1.0183x over previous
//
#include <hip/hip_runtime.h>
#include <math.h>

// B=32, C=3, H=W=512. Low-pass keeps freqs {0,1,2,-3,-2,-1} in both dims.
// Pipeline (3 kernels):
//   k_colsum: 512-thr blocks, (img, 64-row slab); 4 h-quarters x 16 rows/thread,
//             2-deep load pipeline; A[k][w] = sum_h x[h][w] e^{-2pi i k h/512}
//             (k=0..3), phasors by register recurrence; one LDS exchange merges
//             quarters -> Apart[img][8][8][512]
//   k_proj:   blocks 0..95: per img sum 8 partials into LDS As, project 28
//             (k,m) pairs via phasor recurrence -> F[img][56];
//             block 96: build synthesis table tabS[512][12]
//   k_out:    load F, per-row T[c][kc]; per pixel synth via register phasor
//             recurrence, |.|, MLP 3->8 relu ->3, +lp, clip.
//
// ws (floats): tabS @0 (6144), F @6144 (5376), Apart @12288 (3.15M) ~12.6 MB.

#define WS_TS 0
#define WS_F  6144
#define WS_A  12288
constexpr int NPART = 8;

// Block = (img, 64-row slab). 512 threads = 128 w-quads x 4 quarters (16 rows).
__global__ __launch_bounds__(512, 6) void k_colsum(const float* __restrict__ x,
                                                   float* __restrict__ ws) {
    __shared__ float buf[3][128][29];
    float* A = ws + WS_A;
    int img = blockIdx.x >> 3;
    int slab = blockIdx.x & 7;
    int t = threadIdx.x;
    int wq = t & 127;
    int q = t >> 7;                      // quarter 0..3
    int h0 = slab * 64 + q * 16;
    const float* xp = x + (size_t)img * 262144 + (size_t)h0 * 512 + wq * 4;

    const float TH = 6.28318530717958647692f / 512.0f;
    float pc1, ps1, pc2, ps2, pc3, ps3;
    sincosf(TH * (float)h0, &ps1, &pc1);
    pc2 = pc1 * pc1 - ps1 * ps1;  ps2 = 2.f * pc1 * ps1;
    pc3 = pc1 * pc2 - ps1 * ps2;  ps3 = ps1 * pc2 + pc1 * ps2;
    const float C1 = 0.99992470183914450299f, S1 = 0.01227153828571992539f;
    const float C2 = 0.99969881869620422012f, S2 = 0.02454122852291228803f;
    const float C3 = 0.99932238458834954375f, S3 = 0.03680722294135883171f;

    float s0[4] = {0,0,0,0};
    float ar1[4] = {0,0,0,0}, ai1[4] = {0,0,0,0};
    float ar2[4] = {0,0,0,0}, ai2[4] = {0,0,0,0};
    float ar3[4] = {0,0,0,0}, ai3[4] = {0,0,0,0};

    // 2-deep pipeline over 4 groups of 4 rows
    float4 cur[4], nxt[4];
#pragma unroll
    for (int j = 0; j < 4; ++j) cur[j] = *(const float4*)(xp + (size_t)j * 512);
#pragma unroll
    for (int g = 0; g < 4; ++g) {
        if (g < 3) {
#pragma unroll
            for (int j = 0; j < 4; ++j)
                nxt[j] = *(const float4*)(xp + (size_t)((g + 1) * 4 + j) * 512);
        }
#pragma unroll
        for (int j = 0; j < 4; ++j) {
            float xa[4] = {cur[j].x, cur[j].y, cur[j].z, cur[j].w};
#pragma unroll
            for (int u = 0; u < 4; ++u) {
                s0[u] += xa[u];
                ar1[u] = fmaf(xa[u], pc1, ar1[u]);  ai1[u] = fmaf(-xa[u], ps1, ai1[u]);
                ar2[u] = fmaf(xa[u], pc2, ar2[u]);  ai2[u] = fmaf(-xa[u], ps2, ai2[u]);
                ar3[u] = fmaf(xa[u], pc3, ar3[u]);  ai3[u] = fmaf(-xa[u], ps3, ai3[u]);
            }
            float n;
            n = pc1 * C1 - ps1 * S1;  ps1 = ps1 * C1 + pc1 * S1;  pc1 = n;
            n = pc2 * C2 - ps2 * S2;  ps2 = ps2 * C2 + pc2 * S2;  pc2 = n;
            n = pc3 * C3 - ps3 * S3;  ps3 = ps3 * C3 + pc3 * S3;  pc3 = n;
        }
#pragma unroll
        for (int j = 0; j < 4; ++j) cur[j] = nxt[j];
    }

    // merge quarters: 1,2,3 write 28 floats; quarter 0 sums + stores
    if (q != 0) {
        float* r = &buf[q - 1][wq][0];
#pragma unroll
        for (int u = 0; u < 4; ++u) {
            r[u]      = s0[u];
            r[4 + u]  = ar1[u];  r[8 + u]  = ai1[u];
            r[12 + u] = ar2[u];  r[16 + u] = ai2[u];
            r[20 + u] = ar3[u];  r[24 + u] = ai3[u];
        }
    }
    __syncthreads();
    if (q == 0) {
#pragma unroll
        for (int v = 0; v < 3; ++v) {
            const float* r = &buf[v][wq][0];
#pragma unroll
            for (int u = 0; u < 4; ++u) {
                s0[u]  += r[u];
                ar1[u] += r[4 + u];   ai1[u] += r[8 + u];
                ar2[u] += r[12 + u];  ai2[u] += r[16 + u];
                ar3[u] += r[20 + u];  ai3[u] += r[24 + u];
            }
        }
        float* Ab = A + (((size_t)img * NPART + slab) * 8) * 512 + wq * 4;
        *(float4*)(Ab + 0 * 512) = make_float4(s0[0], s0[1], s0[2], s0[3]);
        *(float4*)(Ab + 1 * 512) = make_float4(0.f, 0.f, 0.f, 0.f);
        *(float4*)(Ab + 2 * 512) = make_float4(ar1[0], ar1[1], ar1[2], ar1[3]);
        *(float4*)(Ab + 3 * 512) = make_float4(ai1[0], ai1[1], ai1[2], ai1[3]);
        *(float4*)(Ab + 4 * 512) = make_float4(ar2[0], ar2[1], ar2[2], ar2[3]);
        *(float4*)(Ab + 5 * 512) = make_float4(ai2[0], ai2[1], ai2[2], ai2[3]);
        *(float4*)(Ab + 6 * 512) = make_float4(ar3[0], ar3[1], ar3[2], ar3[3]);
        *(float4*)(Ab + 7 * 512) = make_float4(ai3[0], ai3[1], ai3[2], ai3[3]);
    }
}

// Blocks 0..95: per-image projection. Block 96: build tabS.
__global__ __launch_bounds__(256) void k_proj(float* __restrict__ ws) {
    int t = threadIdx.x;
    if (blockIdx.x == 96) {
        const float STEP = 6.28318530717958647692f / 512.0f;
        const int mv[6] = {0, 1, 2, -3, -2, -1};
        for (int h = t; h < 512; h += 256) {
            float* tsp = ws + WS_TS + h * 12;
#pragma unroll
            for (int i = 0; i < 6; ++i) {
                int r = ((mv[i] * h) % 512 + 512) & 511;
                float s, c;
                sincosf(STEP * (float)r, &s, &c);
                tsp[2 * i] = c; tsp[2 * i + 1] = s;
            }
        }
        return;
    }
    __shared__ float As[8][8][68];    // [plane][seg][j], pad 68
    __shared__ float Rs[28][8][2];
    const float* A = ws + WS_A;
    float* F = ws + WS_F;
    int img = blockIdx.x;

    {   // t -> (plane, 16 consecutive w)
        int plane = t >> 5;
        int w0 = (t & 31) * 16;
        float4 acc[4];
#pragma unroll
        for (int u = 0; u < 4; ++u) acc[u] = make_float4(0.f, 0.f, 0.f, 0.f);
        const float* base = A + ((size_t)img * NPART * 8 + plane) * 512 + w0;
        for (int hg = 0; hg < NPART; ++hg) {
            const float* p = base + (size_t)hg * 8 * 512;
#pragma unroll
            for (int u = 0; u < 4; ++u) {
                float4 v = *(const float4*)(p + u * 4);
                acc[u].x += v.x; acc[u].y += v.y; acc[u].z += v.z; acc[u].w += v.w;
            }
        }
        int seg = w0 >> 6, j0 = w0 & 63;
#pragma unroll
        for (int u = 0; u < 4; ++u)
            *(float4*)&As[plane][seg][j0 + u * 4] = acc[u];
    }
    __syncthreads();

    if (t < 224) {
        int pair = t >> 3, seg = t & 7;
        int k = pair / 7, mi = pair % 7;
        float m = (float)(mi - 3);
        const float TH = 6.28318530717958647692f / 512.0f;
        float cm, sm, pc, ps;
        sincosf(-m * TH, &sm, &cm);                       // e^{-i m theta}
        sincosf(-m * TH * (float)(seg * 64), &ps, &pc);   // e^{-i m w0 theta}
        const float* Ar_ = &As[2 * k][seg][0];
        const float* Ai_ = &As[2 * k + 1][seg][0];
        float pre = 0.f, pim = 0.f;
#pragma unroll 4
        for (int j = 0; j < 64; ++j) {
            float Ar = Ar_[j], Ai = Ai_[j];
            pre += Ar * pc - Ai * ps;
            pim += Ar * ps + Ai * pc;
            float n = pc * cm - ps * sm;
            ps = ps * cm + pc * sm;
            pc = n;
        }
        Rs[pair][seg][0] = pre;
        Rs[pair][seg][1] = pim;
    }
    __syncthreads();
    if (t < 56) {
        int pair = t >> 1, part = t & 1;
        float s = 0.f;
#pragma unroll
        for (int g = 0; g < 8; ++g) s += Rs[pair][g][part];
        F[(size_t)img * 56 + t] = s;
    }
}

__global__ __launch_bounds__(256) void k_out(const float* __restrict__ ws,
                                             const float* __restrict__ w1,
                                             const float* __restrict__ b1,
                                             const float* __restrict__ w2,
                                             const float* __restrict__ b2,
                                             float* __restrict__ out) {
    const float* tabS = ws + WS_TS;
    const float* Fb = ws + WS_F;
    __shared__ float F_lds[3][56];
    __shared__ float T[4][3][12];
    int t = threadIdx.x;
    int blk = blockIdx.x;
    int b = blk >> 7;
    int h0 = (blk & 127) << 2;

    if (t < 168) {
        int c = t / 56, comp = t % 56;
        F_lds[c][comp] = Fb[(size_t)(b * 3 + c) * 56 + comp];
    }

    float rw1[8][3], rb1[8], rw2[3][8], rb2[3];
#pragma unroll
    for (int f_ = 0; f_ < 8; ++f_) {
        rb1[f_] = b1[f_];
#pragma unroll
        for (int c = 0; c < 3; ++c) rw1[f_][c] = w1[f_ * 3 + c];
    }
#pragma unroll
    for (int c = 0; c < 3; ++c) {
        rb2[c] = b2[c];
#pragma unroll
        for (int f_ = 0; f_ < 8; ++f_) rw2[c][f_] = w2[c * 8 + f_];
    }
    __syncthreads();

    if (t < 72) {
        int rl = t / 18, rem = t % 18;
        int c = rem / 6, kc = rem % 6;
        int h = h0 + rl;
        const float* th = tabS + h * 12;
        int m_kc = (kc < 3) ? kc : kc - 6;
        const float inv = 1.0f / (512.0f * 512.0f);
        float tre = 0.f, tim = 0.f;
#pragma unroll
        for (int kr = 0; kr < 6; ++kr) {
            int kk, mi; float csign;
            if (kr < 3) { kk = kr;     mi = m_kc + 3; csign =  1.f; }
            else        { kk = 6 - kr; mi = 3 - m_kc; csign = -1.f; }
            int pair = kk * 7 + mi;
            float fr = F_lds[c][pair * 2] * inv;
            float fi = F_lds[c][pair * 2 + 1] * csign * inv;
            float cc = th[kr * 2], ss = th[kr * 2 + 1];
            tre += fr * cc - fi * ss;
            tim += fr * ss + fi * cc;
        }
        T[rl][c][kc * 2]     = tre;
        T[rl][c][kc * 2 + 1] = tim;
    }
    __syncthreads();

    int rl = t >> 6, lane = t & 63;
    int h = h0 + rl;
    float A0r[3], A0i[3], U1r[3], U1i[3], V1r[3], V1i[3];
    float U2r[3], U2i[3], V2r[3], V2i[3], Br[3], Bi[3];
#pragma unroll
    for (int c = 0; c < 3; ++c) {
        const float* Tc = T[rl][c];
        A0r[c] = Tc[0];  A0i[c] = Tc[1];
        float t1r = Tc[2],  t1i = Tc[3];
        float t2r = Tc[4],  t2i = Tc[5];
        float bmr = Tc[6],  bmi = Tc[7];
        float m2r = Tc[8],  m2i = Tc[9];
        float m1r = Tc[10], m1i = Tc[11];
        U1r[c] = t1r + m1r; U1i[c] = t1i + m1i;
        V1r[c] = t1r - m1r; V1i[c] = t1i - m1i;
        U2r[c] = t2r + m2r; U2i[c] = t2i + m2i;
        V2r[c] = t2r - m2r; V2i[c] = t2i - m2i;
        Br[c] = bmr; Bi[c] = bmi;
    }
    const float* tw = tabS + lane * 12;
    float c1 = tw[2], s1 = tw[3];
    float c2 = tw[4], s2 = tw[5];
    float c3 = tw[6], s3 = -tw[7];
    const float K = 0.70710678118654752440f;
    float* ob = out + ((size_t)(b * 3) * 512 + h) * 512;

#pragma unroll
    for (int j = 0; j < 8; ++j) {
        int w = lane + 64 * j;
        float lp[3];
#pragma unroll
        for (int c = 0; c < 3; ++c) {
            float re = A0r[c] + U1r[c] * c1 - V1i[c] * s1
                              + U2r[c] * c2 - V2i[c] * s2
                              + Br[c] * c3 + Bi[c] * s3;
            float im = A0i[c] + U1i[c] * c1 + V1r[c] * s1
                              + U2i[c] * c2 + V2r[c] * s2
                              + Bi[c] * c3 - Br[c] * s3;
            lp[c] = sqrtf(re * re + im * im);
        }
        float hid[8];
#pragma unroll
        for (int f_ = 0; f_ < 8; ++f_) {
            float v = rb1[f_] + lp[0] * rw1[f_][0] + lp[1] * rw1[f_][1] + lp[2] * rw1[f_][2];
            hid[f_] = fmaxf(v, 0.0f);
        }
#pragma unroll
        for (int c = 0; c < 3; ++c) {
            float y = rb2[c] + lp[c];
#pragma unroll
            for (int f_ = 0; f_ < 8; ++f_) y += hid[f_] * rw2[c][f_];
            y = fminf(fmaxf(y, 0.0f), 1.0f);
            ob[(size_t)c * 262144 + w] = y;
        }
        if (j < 7) {
            float nc1 = K * (c1 - s1), ns1 = K * (c1 + s1);
            float nc2 = -s2,           ns2 = c2;
            float nc3 = -K * (c3 + s3), ns3 = K * (c3 - s3);
            c1 = nc1; s1 = ns1; c2 = nc2; s2 = ns2; c3 = nc3; s3 = ns3;
        }
    }
}

extern "C" void kernel_launch(void* const* d_in, const int* in_sizes, int n_in,
                              void* d_out, int out_size, void* d_ws, size_t ws_size,
                              hipStream_t stream) {
    const float* x  = (const float*)d_in[0];
    const float* w1 = (const float*)d_in[1];
    const float* b1 = (const float*)d_in[2];
    const float* w2 = (const float*)d_in[3];
    const float* b2 = (const float*)d_in[4];
    float* out = (float*)d_out;
    float* ws = (float*)d_ws;

    hipLaunchKernelGGL(k_colsum, dim3(96 * NPART), dim3(512), 0, stream, x, ws);
    hipLaunchKernelGGL(k_proj, dim3(97), dim3(256), 0, stream, ws);
    hipLaunchKernelGGL(k_out, dim3(4096), dim3(256), 0, stream, ws, w1, b1, w2, b2, out);
}

// Round 8
// 66.512 us; speedup vs baseline: 1.4481x; 1.0485x over previous
//
#include <hip/hip_runtime.h>
#include <math.h>

// B=32, C=3, H=W=512. Low-pass keeps freqs {0,1,2,-3,-2,-1} in both dims.
// Pipeline (3 kernels):
//   k_colsum: radix-2 fold over h (rows h, h+256): u=a+b feeds k=0,2; v=a-b
//             feeds k=1,3. Per-row twiddles derived from one base phasor by
//             compile-time rotations (NO loop-carried chain). 8 unrolled
//             iterations x 2 independent float2 loads. 4 waves/block cover 4
//             h-subchunks of one (img, hgrp, w-stripe); LDS-merge ->
//             Apart[img][8][plane 8][512]
//   k_proj:   blocks 0..95: per img sum 8 partials into LDS As, project 28
//             (k,m) pairs via phasor recurrence -> F[img][56];
//             block 96: build synthesis table tabS[512][12]
//   k_out:    load F, per-row T[c][kc]; per pixel synth via register phasor
//             recurrence, |.|, MLP 3->8 relu ->3, +lp, clip.
//
// ws (floats): tabS @0 (6144), F @6144 (5376), Apart @12288 (3.15M) ~12.6 MB.

#define WS_TS 0
#define WS_F  6144
#define WS_A  12288
constexpr int NPART = 8;

// cos/sin(2*pi*n/512), n = 0..7 (compile-time rotation constants)
#define CJ0 1.0f
#define CJ1 0.99992470183914450299f
#define CJ2 0.99969881869620422012f
#define CJ3 0.99932238458834954375f
#define CJ4 0.99879545620517239271f
#define CJ5 0.99811811290014917919f
#define CJ6 0.99729045667869021614f
#define CJ7 0.99631261218277800129f
#define SJ0 0.0f
#define SJ1 0.01227153828571992539f
#define SJ2 0.02454122852291228803f
#define SJ3 0.03680722294135883171f
#define SJ4 0.04906767432741801425f
#define SJ5 0.06132073630220857829f
#define SJ6 0.07356456359966742631f
#define SJ7 0.08579731234443989385f

// Block = (img, hgrp, w-stripe). 256 thr: wave = h-subchunk, lane -> w-pair.
__global__ __launch_bounds__(256, 6) void k_colsum(const float* __restrict__ x,
                                                   float* __restrict__ ws) {
    __shared__ float buf[3][64][15];
    float* A = ws + WS_A;
    int img = blockIdx.x >> 5;
    int sub = blockIdx.x & 31;
    int stripe = sub & 3;            // 128-w stripe
    int hgrp = sub >> 2;             // 8 h-groups of 32 rows (x2 folds)
    int t = threadIdx.x;
    int wave = t >> 6;
    int lane = t & 63;
    int w = stripe * 128 + lane * 2;
    int H = hgrp * 32 + wave * 8;    // first row of this thread's 8
    const float* xp = x + (size_t)img * 262144 + (size_t)H * 512 + w;

    const float TH = 6.28318530717958647692f / 512.0f;
    float pc1, ps1, pc2, ps2, pc3, ps3;
    sincosf(TH * (float)H, &ps1, &pc1);
    pc2 = pc1 * pc1 - ps1 * ps1;  ps2 = 2.f * pc1 * ps1;
    pc3 = pc1 * pc2 - ps1 * ps2;  ps3 = ps1 * pc2 + pc1 * ps2;

    float s0[2] = {0, 0};
    float ar1[2] = {0, 0}, ai1[2] = {0, 0};
    float ar2[2] = {0, 0}, ai2[2] = {0, 0};
    float ar3[2] = {0, 0}, ai3[2] = {0, 0};

#define ROW(J, CJ, SJ)                                                        \
    {                                                                         \
        float2 xa = *(const float2*)(xp + (size_t)(J) * 512);                 \
        float2 xb = *(const float2*)(xp + (size_t)((J) * 512 + 131072));      \
        float u0 = xa.x + xb.x, u1 = xa.y + xb.y;                             \
        float v0 = xa.x - xb.x, v1 = xa.y - xb.y;                             \
        float cj1 = pc1 * (CJ) - ps1 * (SJ);                                  \
        float sj1 = ps1 * (CJ) + pc1 * (SJ);                                  \
        float cj2 = cj1 * cj1 - sj1 * sj1;                                    \
        float sj2 = 2.f * cj1 * sj1;                                          \
        float cj3 = cj1 * cj2 - sj1 * sj2;                                    \
        float sj3 = sj1 * cj2 + cj1 * sj2;                                    \
        s0[0] += u0;               s0[1] += u1;                               \
        ar1[0] = fmaf(v0, cj1, ar1[0]);  ai1[0] = fmaf(-v0, sj1, ai1[0]);     \
        ar1[1] = fmaf(v1, cj1, ar1[1]);  ai1[1] = fmaf(-v1, sj1, ai1[1]);     \
        ar2[0] = fmaf(u0, cj2, ar2[0]);  ai2[0] = fmaf(-u0, sj2, ai2[0]);     \
        ar2[1] = fmaf(u1, cj2, ar2[1]);  ai2[1] = fmaf(-u1, sj2, ai2[1]);     \
        ar3[0] = fmaf(v0, cj3, ar3[0]);  ai3[0] = fmaf(-v0, sj3, ai3[0]);     \
        ar3[1] = fmaf(v1, cj3, ar3[1]);  ai3[1] = fmaf(-v1, sj3, ai3[1]);     \
    }

    ROW(0, CJ0, SJ0)
    ROW(1, CJ1, SJ1)
    ROW(2, CJ2, SJ2)
    ROW(3, CJ3, SJ3)
    ROW(4, CJ4, SJ4)
    ROW(5, CJ5, SJ5)
    ROW(6, CJ6, SJ6)
    ROW(7, CJ7, SJ7)
#undef ROW

    // merge 4 waves via LDS (stride 15 -> conflict-free), wave 0 stores
    if (wave != 0) {
        float* r = &buf[wave - 1][lane][0];
        r[0] = s0[0];   r[1] = s0[1];
        r[2] = ar1[0];  r[3] = ar1[1];  r[4] = ai1[0];  r[5] = ai1[1];
        r[6] = ar2[0];  r[7] = ar2[1];  r[8] = ai2[0];  r[9] = ai2[1];
        r[10] = ar3[0]; r[11] = ar3[1]; r[12] = ai3[0]; r[13] = ai3[1];
    }
    __syncthreads();
    if (wave == 0) {
#pragma unroll
        for (int v = 0; v < 3; ++v) {
            const float* r = &buf[v][lane][0];
            s0[0] += r[0];   s0[1] += r[1];
            ar1[0] += r[2];  ar1[1] += r[3];  ai1[0] += r[4];  ai1[1] += r[5];
            ar2[0] += r[6];  ar2[1] += r[7];  ai2[0] += r[8];  ai2[1] += r[9];
            ar3[0] += r[10]; ar3[1] += r[11]; ai3[0] += r[12]; ai3[1] += r[13];
        }
        float* Ab = A + (((size_t)img * NPART + hgrp) * 8) * 512 + w;
        *(float2*)(Ab + 0 * 512) = make_float2(s0[0], s0[1]);
        *(float2*)(Ab + 1 * 512) = make_float2(0.f, 0.f);
        *(float2*)(Ab + 2 * 512) = make_float2(ar1[0], ar1[1]);
        *(float2*)(Ab + 3 * 512) = make_float2(ai1[0], ai1[1]);
        *(float2*)(Ab + 4 * 512) = make_float2(ar2[0], ar2[1]);
        *(float2*)(Ab + 5 * 512) = make_float2(ai2[0], ai2[1]);
        *(float2*)(Ab + 6 * 512) = make_float2(ar3[0], ar3[1]);
        *(float2*)(Ab + 7 * 512) = make_float2(ai3[0], ai3[1]);
    }
}

// Blocks 0..95: per-image projection. Block 96: build tabS.
__global__ __launch_bounds__(256) void k_proj(float* __restrict__ ws) {
    int t = threadIdx.x;
    if (blockIdx.x == 96) {
        const float STEP = 6.28318530717958647692f / 512.0f;
        const int mv[6] = {0, 1, 2, -3, -2, -1};
        for (int h = t; h < 512; h += 256) {
            float* tsp = ws + WS_TS + h * 12;
#pragma unroll
            for (int i = 0; i < 6; ++i) {
                int r = ((mv[i] * h) % 512 + 512) & 511;
                float s, c;
                sincosf(STEP * (float)r, &s, &c);
                tsp[2 * i] = c; tsp[2 * i + 1] = s;
            }
        }
        return;
    }
    __shared__ float As[8][8][68];
    __shared__ float Rs[28][8][2];
    const float* A = ws + WS_A;
    float* F = ws + WS_F;
    int img = blockIdx.x;

    {
        int plane = t >> 5;
        int w0 = (t & 31) * 16;
        float4 acc[4];
#pragma unroll
        for (int u = 0; u < 4; ++u) acc[u] = make_float4(0.f, 0.f, 0.f, 0.f);
        const float* base = A + ((size_t)img * NPART * 8 + plane) * 512 + w0;
        for (int hg = 0; hg < NPART; ++hg) {
            const float* p = base + (size_t)hg * 8 * 512;
#pragma unroll
            for (int u = 0; u < 4; ++u) {
                float4 v = *(const float4*)(p + u * 4);
                acc[u].x += v.x; acc[u].y += v.y; acc[u].z += v.z; acc[u].w += v.w;
            }
        }
        int seg = w0 >> 6, j0 = w0 & 63;
#pragma unroll
        for (int u = 0; u < 4; ++u)
            *(float4*)&As[plane][seg][j0 + u * 4] = acc[u];
    }
    __syncthreads();

    if (t < 224) {
        int pair = t >> 3, seg = t & 7;
        int k = pair / 7, mi = pair % 7;
        float m = (float)(mi - 3);
        const float TH = 6.28318530717958647692f / 512.0f;
        float cm, sm, pc, ps;
        sincosf(-m * TH, &sm, &cm);
        sincosf(-m * TH * (float)(seg * 64), &ps, &pc);
        const float* Ar_ = &As[2 * k][seg][0];
        const float* Ai_ = &As[2 * k + 1][seg][0];
        float pre = 0.f, pim = 0.f;
#pragma unroll 4
        for (int j = 0; j < 64; ++j) {
            float Ar = Ar_[j], Ai = Ai_[j];
            pre += Ar * pc - Ai * ps;
            pim += Ar * ps + Ai * pc;
            float n = pc * cm - ps * sm;
            ps = ps * cm + pc * sm;
            pc = n;
        }
        Rs[pair][seg][0] = pre;
        Rs[pair][seg][1] = pim;
    }
    __syncthreads();
    if (t < 56) {
        int pair = t >> 1, part = t & 1;
        float s = 0.f;
#pragma unroll
        for (int g = 0; g < 8; ++g) s += Rs[pair][g][part];
        F[(size_t)img * 56 + t] = s;
    }
}

__global__ __launch_bounds__(256) void k_out(const float* __restrict__ ws,
                                             const float* __restrict__ w1,
                                             const float* __restrict__ b1,
                                             const float* __restrict__ w2,
                                             const float* __restrict__ b2,
                                             float* __restrict__ out) {
    const float* tabS = ws + WS_TS;
    const float* Fb = ws + WS_F;
    __shared__ float F_lds[3][56];
    __shared__ float T[4][3][12];
    int t = threadIdx.x;
    int blk = blockIdx.x;
    int b = blk >> 7;
    int h0 = (blk & 127) << 2;

    if (t < 168) {
        int c = t / 56, comp = t % 56;
        F_lds[c][comp] = Fb[(size_t)(b * 3 + c) * 56 + comp];
    }

    float rw1[8][3], rb1[8], rw2[3][8], rb2[3];
#pragma unroll
    for (int f_ = 0; f_ < 8; ++f_) {
        rb1[f_] = b1[f_];
#pragma unroll
        for (int c = 0; c < 3; ++c) rw1[f_][c] = w1[f_ * 3 + c];
    }
#pragma unroll
    for (int c = 0; c < 3; ++c) {
        rb2[c] = b2[c];
#pragma unroll
        for (int f_ = 0; f_ < 8; ++f_) rw2[c][f_] = w2[c * 8 + f_];
    }
    __syncthreads();

    if (t < 72) {
        int rl = t / 18, rem = t % 18;
        int c = rem / 6, kc = rem % 6;
        int h = h0 + rl;
        const float* th = tabS + h * 12;
        int m_kc = (kc < 3) ? kc : kc - 6;
        const float inv = 1.0f / (512.0f * 512.0f);
        float tre = 0.f, tim = 0.f;
#pragma unroll
        for (int kr = 0; kr < 6; ++kr) {
            int kk, mi; float csign;
            if (kr < 3) { kk = kr;     mi = m_kc + 3; csign =  1.f; }
            else        { kk = 6 - kr; mi = 3 - m_kc; csign = -1.f; }
            int pair = kk * 7 + mi;
            float fr = F_lds[c][pair * 2] * inv;
            float fi = F_lds[c][pair * 2 + 1] * csign * inv;
            float cc = th[kr * 2], ss = th[kr * 2 + 1];
            tre += fr * cc - fi * ss;
            tim += fr * ss + fi * cc;
        }
        T[rl][c][kc * 2]     = tre;
        T[rl][c][kc * 2 + 1] = tim;
    }
    __syncthreads();

    int rl = t >> 6, lane = t & 63;
    int h = h0 + rl;
    float A0r[3], A0i[3], U1r[3], U1i[3], V1r[3], V1i[3];
    float U2r[3], U2i[3], V2r[3], V2i[3], Br[3], Bi[3];
#pragma unroll
    for (int c = 0; c < 3; ++c) {
        const float* Tc = T[rl][c];
        A0r[c] = Tc[0];  A0i[c] = Tc[1];
        float t1r = Tc[2],  t1i = Tc[3];
        float t2r = Tc[4],  t2i = Tc[5];
        float bmr = Tc[6],  bmi = Tc[7];
        float m2r = Tc[8],  m2i = Tc[9];
        float m1r = Tc[10], m1i = Tc[11];
        U1r[c] = t1r + m1r; U1i[c] = t1i + m1i;
        V1r[c] = t1r - m1r; V1i[c] = t1i - m1i;
        U2r[c] = t2r + m2r; U2i[c] = t2i + m2i;
        V2r[c] = t2r - m2r; V2i[c] = t2i - m2i;
        Br[c] = bmr; Bi[c] = bmi;
    }
    const float* tw = tabS + lane * 12;
    float c1 = tw[2], s1 = tw[3];
    float c2 = tw[4], s2 = tw[5];
    float c3 = tw[6], s3 = -tw[7];
    const float K = 0.70710678118654752440f;
    float* ob = out + ((size_t)(b * 3) * 512 + h) * 512;

#pragma unroll
    for (int j = 0; j < 8; ++j) {
        int w = lane + 64 * j;
        float lp[3];
#pragma unroll
        for (int c = 0; c < 3; ++c) {
            float re = A0r[c] + U1r[c] * c1 - V1i[c] * s1
                              + U2r[c] * c2 - V2i[c] * s2
                              + Br[c] * c3 + Bi[c] * s3;
            float im = A0i[c] + U1i[c] * c1 + V1r[c] * s1
                              + U2i[c] * c2 + V2r[c] * s2
                              + Bi[c] * c3 - Br[c] * s3;
            lp[c] = sqrtf(re * re + im * im);
        }
        float hid[8];
#pragma unroll
        for (int f_ = 0; f_ < 8; ++f_) {
            float v = rb1[f_] + lp[0] * rw1[f_][0] + lp[1] * rw1[f_][1] + lp[2] * rw1[f_][2];
            hid[f_] = fmaxf(v, 0.0f);
        }
#pragma unroll
        for (int c = 0; c < 3; ++c) {
            float y = rb2[c] + lp[c];
#pragma unroll
            for (int f_ = 0; f_ < 8; ++f_) y += hid[f_] * rw2[c][f_];
            y = fminf(fmaxf(y, 0.0f), 1.0f);
            ob[(size_t)c * 262144 + w] = y;
        }
        if (j < 7) {
            float nc1 = K * (c1 - s1), ns1 = K * (c1 + s1);
            float nc2 = -s2,           ns2 = c2;
            float nc3 = -K * (c3 + s3), ns3 = K * (c3 - s3);
            c1 = nc1; s1 = ns1; c2 = nc2; s2 = ns2; c3 = nc3; s3 = ns3;
        }
    }
}

extern "C" void kernel_launch(void* const* d_in, const int* in_sizes, int n_in,
                              void* d_out, int out_size, void* d_ws, size_t ws_size,
                              hipStream_t stream) {
    const float* x  = (const float*)d_in[0];
    const float* w1 = (const float*)d_in[1];
    const float* b1 = (const float*)d_in[2];
    const float* w2 = (const float*)d_in[3];
    const float* b2 = (const float*)d_in[4];
    float* out = (float*)d_out;
    float* ws = (float*)d_ws;

    hipLaunchKernelGGL(k_colsum, dim3(96 * 32), dim3(256), 0, stream, x, ws);
    hipLaunchKernelGGL(k_proj, dim3(97), dim3(256), 0, stream, ws);
    hipLaunchKernelGGL(k_out, dim3(4096), dim3(256), 0, stream, ws, w1, b1, w2, b2, out);
}